// Round 1
// baseline (96.695 us; speedup 1.0000x reference)
//
#include <hip/hip_runtime.h>

#define HH_DIM 2048
#define WW_DIM 2048
#define NF 64
#define MAX_DEPTH 12

// Kernel 1: per-frame child indices = argmax over selection logits.
// frame_selection is [NF, 2, NF]; row r = (frame*2 + side). First-max
// semantics (strict >) to match jnp.argmax.
__global__ void child_argmax_kernel(const float* __restrict__ sel,
                                    int* __restrict__ child) {
    int r = threadIdx.x;  // 0..127
    if (r < 2 * NF) {
        const float* row = sel + r * NF;
        float best = row[0];
        int bi = 0;
        #pragma unroll
        for (int j = 1; j < NF; ++j) {
            float v = row[j];
            if (v > best) { best = v; bi = j; }
        }
        child[r] = bi;
    }
}

// Kernel 2: per-pixel descent. Each thread handles 4 consecutive x pixels
// and writes one float4 per color plane (coalesced 16B/lane stores).
__global__ __launch_bounds__(256)
void render_kernel(const float* __restrict__ colors,   // [NF,3]
                   const float* __restrict__ ratios,   // [NF]
                   const int* __restrict__ child,      // [NF*2]
                   float* __restrict__ out) {          // [3,H,W]
    __shared__ float s_ratio[NF];
    __shared__ int   s_child[2 * NF];
    __shared__ float s_col[3 * NF];

    int t = threadIdx.x;
    if (t < NF)      s_ratio[t] = ratios[t];
    if (t < 2 * NF)  s_child[t] = child[t];
    if (t < 3 * NF)  s_col[t]   = colors[t];
    __syncthreads();

    int gid = blockIdx.x * 256 + t;          // 1,048,576 threads total
    int y  = gid >> 9;                        // 512 groups of 4 pixels per row
    int xb = (gid & 511) << 2;                // base x for this thread

    float c0[4], c1[4], c2[4];

    #pragma unroll
    for (int p = 0; p < 4; ++p) {
        int x = xb + p;
        int idx = 0;
        int x0 = 0, y0 = 0, w = WW_DIM, h = HH_DIM;
        for (int d = 0; d < MAX_DEPTH; ++d) {
            if (w < 2 || h < 2) break;       // leaf: region too small
            float ratio = s_ratio[idx];
            int ni;
            if (idx & 1) {                   // vertical split (i % 2 == 1)
                int lw = (int)floorf((float)w * ratio);
                lw = lw < 1 ? 1 : lw;
                bool left = (x - x0) < lw;
                ni = left ? s_child[2 * idx] : s_child[2 * idx + 1];
                if (left) { w = lw; }
                else      { x0 += lw; w -= lw; }
            } else {                         // horizontal split
                int th = (int)floorf((float)h * ratio);
                th = th < 1 ? 1 : th;
                bool left = (y - y0) < th;
                ni = left ? s_child[2 * idx] : s_child[2 * idx + 1];
                if (left) { h = th; }
                else      { y0 += th; h -= th; }
            }
            idx = ni;
        }
        c0[p] = s_col[idx * 3 + 0];
        c1[p] = s_col[idx * 3 + 1];
        c2[p] = s_col[idx * 3 + 2];
    }

    int base = y * WW_DIM + xb;
    const int plane = HH_DIM * WW_DIM;
    *(float4*)(out + base)             = make_float4(c0[0], c0[1], c0[2], c0[3]);
    *(float4*)(out + plane + base)     = make_float4(c1[0], c1[1], c1[2], c1[3]);
    *(float4*)(out + 2 * plane + base) = make_float4(c2[0], c2[1], c2[2], c2[3]);
}

extern "C" void kernel_launch(void* const* d_in, const int* in_sizes, int n_in,
                              void* d_out, int out_size, void* d_ws, size_t ws_size,
                              hipStream_t stream) {
    const float* frame_colors    = (const float*)d_in[0];  // [64,3]
    const float* frame_selection = (const float*)d_in[1];  // [64,2,64]
    const float* split_ratios    = (const float*)d_in[2];  // [64]
    float* out = (float*)d_out;
    int* child = (int*)d_ws;  // 128 ints of scratch

    child_argmax_kernel<<<1, 128, 0, stream>>>(frame_selection, child);

    // 2048 rows * 512 thread-groups/row = 1,048,576 threads -> 4096 blocks
    render_kernel<<<4096, 256, 0, stream>>>(frame_colors, split_ratios, child, out);
}